// Round 2
// baseline (946.663 us; speedup 1.0000x reference)
//
#include <hip/hip_runtime.h>
#include <cstdint>
#include <cstddef>

// ---------------------------------------------------------------------------
// FastQuantumEvolution: 2nd-order Taylor graph evolution.
//   deg[c] = count of c in col (E edges) + 1 (self loop)
//   dis[n] = rsqrt(deg[n])
//   prop(h)[r] += h[c] * dis[r]*dis[c]   over E edges + N self loops
//   fo = prop(x); so = prop(fo)
//   evolved = x + i*c1*fo - (c1^2/2)*so,  c1 = t*s
//   w[n] = sum_d |evolved|^2 ; w *= N / sum(w)
// Output: [ w (N floats) | evolved (real-only N*32  OR  interleaved N*64) ]
// NOTE: harness passes integer inputs as int32 (edge_index int64 -> int32).
// ---------------------------------------------------------------------------

#define TPB 256

__global__ void k_deg(const int* __restrict__ col, int E,
                      float* __restrict__ deg) {
    int stride = gridDim.x * blockDim.x;
    for (int i = blockIdx.x * blockDim.x + threadIdx.x; i < E; i += stride)
        atomicAdd(&deg[col[i]], 1.0f);
}

__global__ void k_dis(float* __restrict__ deg, int N) {
    int i = blockIdx.x * blockDim.x + threadIdx.x;
    if (i < N) deg[i] = rsqrtf(deg[i] + 1.0f);  // +1 = self loop; always > 0
}

// One thread per (edge, feature-dim). 32 consecutive threads share one edge.
__global__ void k_prop(const int* __restrict__ row,
                       const int* __restrict__ col,
                       int E, int N, const float* __restrict__ dis,
                       const float* __restrict__ hr, const float* __restrict__ hi,
                       float* __restrict__ outr, float* __restrict__ outi) {
    long long total  = ((long long)E + N) << 5;
    long long stride = (long long)gridDim.x * blockDim.x;
    for (long long t = (long long)blockIdx.x * blockDim.x + threadIdx.x;
         t < total; t += stride) {
        int e = (int)(t >> 5);
        int d = (int)(t & 31);
        int r, c;
        if (e < E) { r = row[e]; c = col[e]; }
        else       { r = c = e - E; }                    // self loop
        float nrm = dis[r] * dis[c];
        atomicAdd(&outr[r * 32 + d], hr[c * 32 + d] * nrm);
        atomicAdd(&outi[r * 32 + d], hi[c * 32 + d] * nrm);
    }
}

__global__ void k_final(const float* __restrict__ xr, const float* __restrict__ xi,
                        const float* __restrict__ fr, const float* __restrict__ fi,
                        const float* __restrict__ sr, const float* __restrict__ si,
                        const float* __restrict__ tptr, const float* __restrict__ dptr,
                        float* __restrict__ out, int N, long long ND,
                        int interleaved, float* __restrict__ S) {
    long long t = (long long)blockIdx.x * blockDim.x + threadIdx.x;
    float c   = tptr[0] * dptr[0];
    float c2h = 0.5f * c * c;
    float er = 0.0f, ei = 0.0f;
    bool valid = t < ND;
    if (valid) {
        er = xr[t] - c * fi[t] - c2h * sr[t];
        ei = xi[t] + c * fr[t] - c2h * si[t];
        if (interleaved) {
            out[N + 2 * t]     = er;
            out[N + 2 * t + 1] = ei;
        } else {
            out[N + t] = er;
        }
    }
    float wv = er * er + ei * ei;
    // reduce across the 32 lanes sharing a node
    #pragma unroll
    for (int off = 16; off; off >>= 1) wv += __shfl_xor(wv, off, 32);
    if (valid && ((threadIdx.x & 31) == 0)) out[t >> 5] = wv;  // unnormalized w
    // wave total (two nodes per 64-lane wave), then block total -> one atomic
    wv += __shfl_xor(wv, 32, 64);
    __shared__ float ls[TPB / 64];
    int wave = threadIdx.x >> 6;
    if ((threadIdx.x & 63) == 0) ls[wave] = wv;
    __syncthreads();
    if (threadIdx.x == 0) {
        float bs = 0.0f;
        #pragma unroll
        for (int i = 0; i < TPB / 64; ++i) bs += ls[i];
        atomicAdd(S, bs);
    }
}

__global__ void k_norm(float* __restrict__ w, int N, const float* __restrict__ S) {
    int i = blockIdx.x * blockDim.x + threadIdx.x;
    if (i >= N) return;
    float s = *S;
    w[i] = (s > 1e-8f) ? w[i] * ((float)N / s) : 1.0f;
}

extern "C" void kernel_launch(void* const* d_in, const int* in_sizes, int n_in,
                              void* d_out, int out_size, void* d_ws, size_t ws_size,
                              hipStream_t stream) {
    const float* xr   = (const float*)d_in[0];
    const float* xi   = (const float*)d_in[1];
    const int*   eidx = (const int*)d_in[2];   // int64 in ref -> int32 from harness
    const float* tptr = (const float*)d_in[3];
    const float* dptr = (const float*)d_in[4];

    const int N = in_sizes[0] / 32;
    const int E = in_sizes[2] / 2;
    const int* row = eidx;
    const int* col = eidx + E;
    const long long ND = (long long)N * 32;

    // workspace layout (floats): dis[N] | fr[ND] | fi[ND] | sr[ND] | si[ND] | S[1]
    float* ws  = (float*)d_ws;
    float* dis = ws;
    float* fr  = dis + N;
    float* fi  = fr + ND;
    float* sr  = fi + ND;
    float* si  = sr + ND;
    float* S   = si + ND;
    size_t zero_bytes = (size_t)(N + 4 * ND + 1) * sizeof(float);
    hipMemsetAsync(d_ws, 0, zero_bytes, stream);

    // evolved layout in d_out: real-only (out_size == N + ND) or interleaved
    int interleaved = (out_size >= (int)(N + 2 * ND)) ? 1 : 0;

    float* out = (float*)d_out;

    k_deg<<<2048, TPB, 0, stream>>>(col, E, dis);
    k_dis<<<(N + TPB - 1) / TPB, TPB, 0, stream>>>(dis, N);
    k_prop<<<4096, TPB, 0, stream>>>(row, col, E, N, dis, xr, xi, fr, fi);
    k_prop<<<4096, TPB, 0, stream>>>(row, col, E, N, dis, fr, fi, sr, si);
    int fblocks = (int)((ND + TPB - 1) / TPB);
    k_final<<<fblocks, TPB, 0, stream>>>(xr, xi, fr, fi, sr, si, tptr, dptr,
                                         out, N, ND, interleaved, S);
    k_norm<<<(N + TPB - 1) / TPB, TPB, 0, stream>>>(out, N, S);
}

// Round 3
// 494.814 us; speedup vs baseline: 1.9132x; 1.9132x over previous
//
#include <hip/hip_runtime.h>
#include <cstdint>
#include <cstddef>

// ---------------------------------------------------------------------------
// FastQuantumEvolution via CSR gather (no f32 scatter atomics).
//   deg[c] = count of c in col (E edges) + 1 (self loop); dis = rsqrt(deg)
//   prop(h)[r] = h[r]*dis[r]^2 + sum_{e: row[e]=r} h[col[e]]*dis[r]*dis[col[e]]
//   fo = prop(x); evolved = x + i*c1*fo - (c1^2/2)*prop(fo),  c1 = t*s
//   w[n] = sum_d |evolved|^2 ; w *= N / sum(w)
// Output: [ w (N floats) | evolved (real-only N*32 OR interleaved N*64) ]
// Harness passes integer inputs as int32.
// ---------------------------------------------------------------------------

#define TPB 256
#define GPB 8  // 32-lane groups per 256-thread block

__global__ void k_hist(const int* __restrict__ row, const int* __restrict__ col,
                       int E, int* __restrict__ rowcnt, int* __restrict__ colcnt) {
    int stride = gridDim.x * blockDim.x;
    for (int e = blockIdx.x * blockDim.x + threadIdx.x; e < E; e += stride) {
        atomicAdd(&rowcnt[row[e]], 1);
        atomicAdd(&colcnt[col[e]], 1);
    }
}

__global__ void k_dis(const int* __restrict__ colcnt, float* __restrict__ dis, int N) {
    int i = blockIdx.x * blockDim.x + threadIdx.x;
    if (i < N) dis[i] = rsqrtf((float)colcnt[i] + 1.0f);  // +1 self loop
}

// exclusive scan, 1024 elems per 256-thread block
__global__ void k_scan1(const int* __restrict__ in, int* __restrict__ out,
                        int* __restrict__ partials, int N) {
    __shared__ int sh[256];
    int t = threadIdx.x;
    int base = blockIdx.x * 1024 + t * 4;
    int v0 = (base + 0 < N) ? in[base + 0] : 0;
    int v1 = (base + 1 < N) ? in[base + 1] : 0;
    int v2 = (base + 2 < N) ? in[base + 2] : 0;
    int v3 = (base + 3 < N) ? in[base + 3] : 0;
    int s = v0 + v1 + v2 + v3;
    sh[t] = s;
    __syncthreads();
    for (int off = 1; off < 256; off <<= 1) {
        int add = (t >= off) ? sh[t - off] : 0;
        __syncthreads();
        sh[t] += add;
        __syncthreads();
    }
    int excl = sh[t] - s;  // sum of all prior threads in block
    if (base + 0 < N) out[base + 0] = excl;
    excl += v0;
    if (base + 1 < N) out[base + 1] = excl;
    excl += v1;
    if (base + 2 < N) out[base + 2] = excl;
    excl += v2;
    if (base + 3 < N) out[base + 3] = excl;
    if (t == 255) partials[blockIdx.x] = sh[255];
}

__global__ void k_scan2(int* __restrict__ partials, int nb) {
    if (threadIdx.x == 0 && blockIdx.x == 0) {
        int acc = 0;
        for (int i = 0; i < nb; ++i) { int v = partials[i]; partials[i] = acc; acc += v; }
    }
}

__global__ void k_scan3(int* __restrict__ out, const int* __restrict__ partials,
                        int N, int E) {
    int i = blockIdx.x * blockDim.x + threadIdx.x;
    if (i < N) out[i] += partials[i >> 10];
    if (i == 0) out[N] = E;
}

__global__ void k_scatter(const int* __restrict__ row, const int* __restrict__ col,
                          int E, const int* __restrict__ rowptr,
                          int* __restrict__ cursor, const float* __restrict__ dis,
                          int2* __restrict__ entries) {
    int stride = gridDim.x * blockDim.x;
    for (int e = blockIdx.x * blockDim.x + threadIdx.x; e < E; e += stride) {
        int r = row[e], c = col[e];
        int pos = rowptr[r] + atomicAdd(&cursor[r], 1);
        entries[pos] = make_int2(c, __float_as_int(dis[r] * dis[c]));
    }
}

// One 32-lane group per node; lane d owns feature dim d. Registers accumulate.
__global__ void k_prop_csr(const int* __restrict__ rowptr,
                           const int2* __restrict__ entries,
                           const float* __restrict__ dis,
                           const float* __restrict__ hr, const float* __restrict__ hi,
                           float* __restrict__ outr, float* __restrict__ outi, int N) {
    int g = blockIdx.x * GPB + (threadIdx.x >> 5);
    int d = threadIdx.x & 31;
    if (g >= N) return;
    int beg = rowptr[g], end = rowptr[g + 1];
    float dg = dis[g];
    long long gd = (long long)g * 32 + d;
    float aR = hr[gd] * dg * dg;  // self loop
    float aI = hi[gd] * dg * dg;
    for (int base = beg; base < end; base += 32) {
        int m = end - base;
        int2 ent = make_int2(0, 0);
        if (d < m) ent = entries[base + d];
        int lim = m < 32 ? m : 32;
        for (int j = 0; j < lim; ++j) {
            int c = __shfl(ent.x, j, 32);
            float nv = __int_as_float(__shfl(ent.y, j, 32));
            aR += hr[(long long)c * 32 + d] * nv;
            aI += hi[(long long)c * 32 + d] * nv;
        }
    }
    outr[gd] = aR;
    outi[gd] = aI;
}

// Second propagate fused with final combine + |psi|^2 reduction.
__global__ void k_prop_final(const int* __restrict__ rowptr,
                             const int2* __restrict__ entries,
                             const float* __restrict__ dis,
                             const float* __restrict__ xr, const float* __restrict__ xi,
                             const float* __restrict__ fr, const float* __restrict__ fi,
                             const float* __restrict__ tptr, const float* __restrict__ dptr,
                             float* __restrict__ out, int N, int interleaved,
                             float* __restrict__ S) {
    int g = blockIdx.x * GPB + (threadIdx.x >> 5);
    int d = threadIdx.x & 31;
    bool valid = g < N;
    float aR = 0.f, aI = 0.f, foR = 0.f, foI = 0.f, er = 0.f, ei = 0.f;
    if (valid) {
        int beg = rowptr[g], end = rowptr[g + 1];
        float dg = dis[g];
        long long gd = (long long)g * 32 + d;
        foR = fr[gd]; foI = fi[gd];
        aR = foR * dg * dg;  // self loop of second propagate
        aI = foI * dg * dg;
        for (int base = beg; base < end; base += 32) {
            int m = end - base;
            int2 ent = make_int2(0, 0);
            if (d < m) ent = entries[base + d];
            int lim = m < 32 ? m : 32;
            for (int j = 0; j < lim; ++j) {
                int c = __shfl(ent.x, j, 32);
                float nv = __int_as_float(__shfl(ent.y, j, 32));
                aR += fr[(long long)c * 32 + d] * nv;
                aI += fi[(long long)c * 32 + d] * nv;
            }
        }
        float c1  = tptr[0] * dptr[0];
        float c2h = 0.5f * c1 * c1;
        er = xr[gd] - c1 * foI - c2h * aR;
        ei = xi[gd] + c1 * foR - c2h * aI;
        long long t = gd;
        if (interleaved) {
            out[N + 2 * t]     = er;
            out[N + 2 * t + 1] = ei;
        } else {
            out[N + t] = er;
        }
    }
    float wv = er * er + ei * ei;
    #pragma unroll
    for (int off = 16; off; off >>= 1) wv += __shfl_xor(wv, off, 32);
    if (valid && ((threadIdx.x & 31) == 0)) out[g] = wv;  // unnormalized w
    __shared__ float ls[GPB];
    int grp = threadIdx.x >> 5;
    if ((threadIdx.x & 31) == 0) ls[grp] = valid ? wv : 0.f;
    __syncthreads();
    if (threadIdx.x == 0) {
        float bs = 0.f;
        #pragma unroll
        for (int i = 0; i < GPB; ++i) bs += ls[i];
        atomicAdd(S, bs);
    }
}

__global__ void k_norm(float* __restrict__ w, int N, const float* __restrict__ S) {
    int i = blockIdx.x * blockDim.x + threadIdx.x;
    if (i >= N) return;
    float s = *S;
    w[i] = (s > 1e-8f) ? w[i] * ((float)N / s) : 1.0f;
}

extern "C" void kernel_launch(void* const* d_in, const int* in_sizes, int n_in,
                              void* d_out, int out_size, void* d_ws, size_t ws_size,
                              hipStream_t stream) {
    const float* xr   = (const float*)d_in[0];
    const float* xi   = (const float*)d_in[1];
    const int*   eidx = (const int*)d_in[2];   // int64 in ref -> int32 from harness
    const float* tptr = (const float*)d_in[3];
    const float* dptr = (const float*)d_in[4];

    const int N = in_sizes[0] / 32;
    const int E = in_sizes[2] / 2;
    const int* row = eidx;
    const int* col = eidx + E;
    const long long ND = (long long)N * 32;
    const int NB = (N + 1023) / 1024;  // scan blocks

    // ws layout (4B units):
    // [rowcnt N | cursor N | colcnt N | S 1]  <- zeroed
    // [rowptr N+1 | partials NBpad | dis N | fr ND | fi ND | entries 2E]
    int*   rowcnt   = (int*)d_ws;
    int*   cursor   = rowcnt + N;
    int*   colcnt   = cursor + N;
    float* S        = (float*)(colcnt + N);
    int*   rowptr   = (int*)(S + 1);
    int    nbpad    = (NB + 129) & ~1;          // pad, keep even
    int*   partials = rowptr + (N + 1);
    float* dis      = (float*)(partials + nbpad);
    float* fr       = dis + N;
    float* fi       = fr + ND;
    size_t ent_off  = (size_t)(fi + ND - (float*)d_ws);
    ent_off = (ent_off + 1) & ~(size_t)1;       // 8B align
    int2*  entries  = (int2*)((float*)d_ws + ent_off);

    hipMemsetAsync(d_ws, 0, (size_t)(3 * N + 1) * sizeof(int), stream);

    int interleaved = (out_size >= (int)(N + 2 * ND)) ? 1 : 0;
    float* out = (float*)d_out;

    k_hist<<<2048, TPB, 0, stream>>>(row, col, E, rowcnt, colcnt);
    k_dis<<<(N + TPB - 1) / TPB, TPB, 0, stream>>>(colcnt, dis, N);
    k_scan1<<<NB, TPB, 0, stream>>>(rowcnt, rowptr, partials, N);
    k_scan2<<<1, 64, 0, stream>>>(partials, NB);
    k_scan3<<<(N + TPB - 1) / TPB, TPB, 0, stream>>>(rowptr, partials, N, E);
    k_scatter<<<2048, TPB, 0, stream>>>(row, col, E, rowptr, cursor, dis, entries);

    int pblocks = (N + GPB - 1) / GPB;
    k_prop_csr<<<pblocks, TPB, 0, stream>>>(rowptr, entries, dis, xr, xi, fr, fi, N);
    k_prop_final<<<pblocks, TPB, 0, stream>>>(rowptr, entries, dis, xr, xi, fr, fi,
                                              tptr, dptr, out, N, interleaved, S);
    k_norm<<<(N + TPB - 1) / TPB, TPB, 0, stream>>>(out, N, S);
}

// Round 4
// 472.665 us; speedup vs baseline: 2.0028x; 1.0469x over previous
//
#include <hip/hip_runtime.h>
#include <cstdint>
#include <cstddef>

// ---------------------------------------------------------------------------
// FastQuantumEvolution via CSR gather, bf16-packed neighbor features.
//   deg[c] = count of c in col (+1 self loop); dis = rsqrt(deg)
//   prop(h)[r] = h[r]*dis[r]^2 + sum_{e: row[e]=r} h[col[e]]*dis[r]*dis[col[e]]
//   fo = prop(x); evolved = x + i*c1*fo - (c1^2/2)*prop(fo),  c1 = t*s
//   w[n] = sum_d |evolved|^2 ; w *= N / sum(w)
// Output: [ w (N floats) | evolved (real-only N*32 OR interleaved N*64) ]
// ---------------------------------------------------------------------------

#define TPB 256
#define GPB 8  // 32-lane groups per 256-thread block

__device__ __forceinline__ uint32_t f2bf(float f) {
    uint32_t u = __float_as_uint(f);
    return (u + 0x7FFFu + ((u >> 16) & 1u)) >> 16;  // RNE
}
__device__ __forceinline__ uint32_t pack2(float re, float im) {
    return f2bf(re) | (f2bf(im) << 16);
}
__device__ __forceinline__ float bflo(uint32_t p) { return __uint_as_float(p << 16); }
__device__ __forceinline__ float bfhi(uint32_t p) { return __uint_as_float(p & 0xFFFF0000u); }

__global__ void k_hist(const int* __restrict__ row, const int* __restrict__ col,
                       int E, int* __restrict__ rowcnt, int* __restrict__ colcnt) {
    int stride = gridDim.x * blockDim.x;
    for (int e = blockIdx.x * blockDim.x + threadIdx.x; e < E; e += stride) {
        atomicAdd(&rowcnt[row[e]], 1);
        atomicAdd(&colcnt[col[e]], 1);
    }
}

__global__ void k_dis(const int* __restrict__ colcnt, float* __restrict__ dis, int N) {
    int i = blockIdx.x * blockDim.x + threadIdx.x;
    if (i < N) dis[i] = rsqrtf((float)colcnt[i] + 1.0f);
}

__global__ void k_pack(const float* __restrict__ xr, const float* __restrict__ xi,
                       uint32_t* __restrict__ xb, long long ND) {
    long long i = (long long)blockIdx.x * blockDim.x + threadIdx.x;
    if (i < ND) xb[i] = pack2(xr[i], xi[i]);
}

// exclusive scan, 1024 elems per 256-thread block
__global__ void k_scan1(const int* __restrict__ in, int* __restrict__ out,
                        int* __restrict__ partials, int N) {
    __shared__ int sh[256];
    int t = threadIdx.x;
    int base = blockIdx.x * 1024 + t * 4;
    int v0 = (base + 0 < N) ? in[base + 0] : 0;
    int v1 = (base + 1 < N) ? in[base + 1] : 0;
    int v2 = (base + 2 < N) ? in[base + 2] : 0;
    int v3 = (base + 3 < N) ? in[base + 3] : 0;
    int s = v0 + v1 + v2 + v3;
    sh[t] = s;
    __syncthreads();
    for (int off = 1; off < 256; off <<= 1) {
        int add = (t >= off) ? sh[t - off] : 0;
        __syncthreads();
        sh[t] += add;
        __syncthreads();
    }
    int excl = sh[t] - s;
    if (base + 0 < N) out[base + 0] = excl;
    excl += v0;
    if (base + 1 < N) out[base + 1] = excl;
    excl += v1;
    if (base + 2 < N) out[base + 2] = excl;
    excl += v2;
    if (base + 3 < N) out[base + 3] = excl;
    if (t == 255) partials[blockIdx.x] = sh[255];
}

__global__ void k_scan2(int* __restrict__ partials, int nb) {
    if (threadIdx.x == 0 && blockIdx.x == 0) {
        int acc = 0;
        for (int i = 0; i < nb; ++i) { int v = partials[i]; partials[i] = acc; acc += v; }
    }
}

__global__ void k_scan3(int* __restrict__ out, const int* __restrict__ partials,
                        int N, int E) {
    int i = blockIdx.x * blockDim.x + threadIdx.x;
    if (i < N) out[i] += partials[i >> 10];
    if (i == 0) out[N] = E;
}

__global__ void k_scatter(const int* __restrict__ row, const int* __restrict__ col,
                          int E, const int* __restrict__ rowptr,
                          int* __restrict__ cursor, const float* __restrict__ dis,
                          int2* __restrict__ entries) {
    int stride = gridDim.x * blockDim.x;
    for (int e = blockIdx.x * blockDim.x + threadIdx.x; e < E; e += stride) {
        int r = row[e], c = col[e];
        int pos = rowptr[r] + atomicAdd(&cursor[r], 1);
        entries[pos] = make_int2(c, __float_as_int(dis[r] * dis[c]));
    }
}

// Shared edge-accumulation: gather packed bf16 neighbor features.
__device__ __forceinline__ void edge_accum(const int2* __restrict__ entries,
                                           const uint32_t* __restrict__ hb,
                                           int beg, int end, int d,
                                           float& aR, float& aI) {
    int j = beg;
    for (; j + 8 <= end; j += 8) {
        int2 e0 = entries[j + 0], e1 = entries[j + 1];
        int2 e2 = entries[j + 2], e3 = entries[j + 3];
        int2 e4 = entries[j + 4], e5 = entries[j + 5];
        int2 e6 = entries[j + 6], e7 = entries[j + 7];
        uint32_t p0 = hb[(size_t)e0.x * 32 + d];
        uint32_t p1 = hb[(size_t)e1.x * 32 + d];
        uint32_t p2 = hb[(size_t)e2.x * 32 + d];
        uint32_t p3 = hb[(size_t)e3.x * 32 + d];
        uint32_t p4 = hb[(size_t)e4.x * 32 + d];
        uint32_t p5 = hb[(size_t)e5.x * 32 + d];
        uint32_t p6 = hb[(size_t)e6.x * 32 + d];
        uint32_t p7 = hb[(size_t)e7.x * 32 + d];
        float n0 = __int_as_float(e0.y), n1 = __int_as_float(e1.y);
        float n2 = __int_as_float(e2.y), n3 = __int_as_float(e3.y);
        float n4 = __int_as_float(e4.y), n5 = __int_as_float(e5.y);
        float n6 = __int_as_float(e6.y), n7 = __int_as_float(e7.y);
        aR += bflo(p0) * n0; aI += bfhi(p0) * n0;
        aR += bflo(p1) * n1; aI += bfhi(p1) * n1;
        aR += bflo(p2) * n2; aI += bfhi(p2) * n2;
        aR += bflo(p3) * n3; aI += bfhi(p3) * n3;
        aR += bflo(p4) * n4; aI += bfhi(p4) * n4;
        aR += bflo(p5) * n5; aI += bfhi(p5) * n5;
        aR += bflo(p6) * n6; aI += bfhi(p6) * n6;
        aR += bflo(p7) * n7; aI += bfhi(p7) * n7;
    }
    for (; j < end; ++j) {
        int2 e = entries[j];
        uint32_t p = hb[(size_t)e.x * 32 + d];
        float nv = __int_as_float(e.y);
        aR += bflo(p) * nv;
        aI += bfhi(p) * nv;
    }
}

// First propagate: gather xb, write fo (f32 pairs) + fob (bf16 packed).
__global__ void k_prop1(const int* __restrict__ rowptr,
                        const int2* __restrict__ entries,
                        const float* __restrict__ dis,
                        const float* __restrict__ xr, const float* __restrict__ xi,
                        const uint32_t* __restrict__ xb,
                        float2* __restrict__ fo2, uint32_t* __restrict__ fob, int N) {
    int g = blockIdx.x * GPB + (threadIdx.x >> 5);
    int d = threadIdx.x & 31;
    if (g >= N) return;
    int beg = rowptr[g], end = rowptr[g + 1];
    float dg = dis[g];
    long long gd = (long long)g * 32 + d;
    float aR = xr[gd] * dg * dg;  // self loop (exact f32 x)
    float aI = xi[gd] * dg * dg;
    edge_accum(entries, xb, beg, end, d, aR, aI);
    fo2[gd] = make_float2(aR, aI);
    fob[gd] = pack2(aR, aI);
}

// Second propagate fused with final combine + |psi|^2 reduction.
__global__ void k_prop_final(const int* __restrict__ rowptr,
                             const int2* __restrict__ entries,
                             const float* __restrict__ dis,
                             const float* __restrict__ xr, const float* __restrict__ xi,
                             const float2* __restrict__ fo2,
                             const uint32_t* __restrict__ fob,
                             const float* __restrict__ tptr, const float* __restrict__ dptr,
                             float* __restrict__ out, int N, int interleaved,
                             float* __restrict__ S) {
    int g = blockIdx.x * GPB + (threadIdx.x >> 5);
    int d = threadIdx.x & 31;
    bool valid = g < N;
    float er = 0.f, ei = 0.f;
    if (valid) {
        int beg = rowptr[g], end = rowptr[g + 1];
        float dg = dis[g];
        long long gd = (long long)g * 32 + d;
        float2 fo = fo2[gd];
        float aR = fo.x * dg * dg;  // self loop of second propagate
        float aI = fo.y * dg * dg;
        edge_accum(entries, fob, beg, end, d, aR, aI);
        float c1  = tptr[0] * dptr[0];
        float c2h = 0.5f * c1 * c1;
        er = xr[gd] - c1 * fo.y - c2h * aR;
        ei = xi[gd] + c1 * fo.x - c2h * aI;
        if (interleaved) {
            out[N + 2 * gd]     = er;
            out[N + 2 * gd + 1] = ei;
        } else {
            out[N + gd] = er;
        }
    }
    float wv = er * er + ei * ei;
    #pragma unroll
    for (int off = 16; off; off >>= 1) wv += __shfl_xor(wv, off, 32);
    if (valid && ((threadIdx.x & 31) == 0)) out[g] = wv;  // unnormalized w
    __shared__ float ls[GPB];
    int grp = threadIdx.x >> 5;
    if ((threadIdx.x & 31) == 0) ls[grp] = valid ? wv : 0.f;
    __syncthreads();
    if (threadIdx.x == 0) {
        float bs = 0.f;
        #pragma unroll
        for (int i = 0; i < GPB; ++i) bs += ls[i];
        atomicAdd(S, bs);
    }
}

__global__ void k_norm(float* __restrict__ w, int N, const float* __restrict__ S) {
    int i = blockIdx.x * blockDim.x + threadIdx.x;
    if (i >= N) return;
    float s = *S;
    w[i] = (s > 1e-8f) ? w[i] * ((float)N / s) : 1.0f;
}

extern "C" void kernel_launch(void* const* d_in, const int* in_sizes, int n_in,
                              void* d_out, int out_size, void* d_ws, size_t ws_size,
                              hipStream_t stream) {
    const float* xr   = (const float*)d_in[0];
    const float* xi   = (const float*)d_in[1];
    const int*   eidx = (const int*)d_in[2];
    const float* tptr = (const float*)d_in[3];
    const float* dptr = (const float*)d_in[4];

    const int N = in_sizes[0] / 32;
    const int E = in_sizes[2] / 2;
    const int* row = eidx;
    const int* col = eidx + E;
    const long long ND = (long long)N * 32;
    const int NB = (N + 1023) / 1024;

    // ws layout (4B units):
    // [rowcnt N | cursor N | colcnt N | S 1] <- zeroed
    // [rowptr N+1 | partials nbpad | dis N | xb ND | fo2 2*ND | fob ND | entries 2E]
    int*      rowcnt   = (int*)d_ws;
    int*      cursor   = rowcnt + N;
    int*      colcnt   = cursor + N;
    float*    S        = (float*)(colcnt + N);
    int*      rowptr   = (int*)(S + 1);
    int       nbpad    = (NB + 3) & ~1;
    int*      partials = rowptr + (N + 1);
    float*    dis      = (float*)(partials + nbpad);
    uint32_t* xb       = (uint32_t*)(dis + N);
    size_t off = (size_t)((int*)xb - (int*)d_ws) + ND;
    off = (off + 1) & ~(size_t)1;  // 8B align
    float2*   fo2      = (float2*)((int*)d_ws + off);
    uint32_t* fob      = (uint32_t*)(fo2 + ND);
    size_t off2 = (size_t)((int*)fob - (int*)d_ws) + ND;
    off2 = (off2 + 1) & ~(size_t)1;
    int2*     entries  = (int2*)((int*)d_ws + off2);

    hipMemsetAsync(d_ws, 0, (size_t)(3 * N + 1) * sizeof(int), stream);

    int interleaved = (out_size >= (int)(N + 2 * ND)) ? 1 : 0;
    float* out = (float*)d_out;

    k_hist<<<2048, TPB, 0, stream>>>(row, col, E, rowcnt, colcnt);
    k_dis<<<(N + TPB - 1) / TPB, TPB, 0, stream>>>(colcnt, dis, N);
    k_pack<<<(int)((ND + TPB - 1) / TPB), TPB, 0, stream>>>(xr, xi, xb, ND);
    k_scan1<<<NB, TPB, 0, stream>>>(rowcnt, rowptr, partials, N);
    k_scan2<<<1, 64, 0, stream>>>(partials, NB);
    k_scan3<<<(N + TPB - 1) / TPB, TPB, 0, stream>>>(rowptr, partials, N, E);
    k_scatter<<<2048, TPB, 0, stream>>>(row, col, E, rowptr, cursor, dis, entries);

    int pblocks = (N + GPB - 1) / GPB;
    k_prop1<<<pblocks, TPB, 0, stream>>>(rowptr, entries, dis, xr, xi, xb, fo2, fob, N);
    k_prop_final<<<pblocks, TPB, 0, stream>>>(rowptr, entries, dis, xr, xi, fo2, fob,
                                              tptr, dptr, out, N, interleaved, S);
    k_norm<<<(N + TPB - 1) / TPB, TPB, 0, stream>>>(out, N, S);
}

// Round 5
// 438.423 us; speedup vs baseline: 2.1592x; 1.0781x over previous
//
#include <hip/hip_runtime.h>
#include <cstdint>
#include <cstddef>

// ---------------------------------------------------------------------------
// FastQuantumEvolution via CSR gather, dis-premultiplied bf16-packed operands.
//   dis = rsqrt(deg_col + 1)
//   prop(h)[r] = dis[r] * ( Sum_{e: row=r} h[c]*dis[c]  +  h[r]*dis[r] )
//   fo = prop(x); evolved = x + i*c1*fo - (c1^2/2)*prop(fo),  c1 = t*s
//   w[n] = sum_d |evolved|^2 ; w *= N / sum(w)
// Output: [ w (N floats) | evolved (real-only N*32 OR interleaved N*64) ]
// ---------------------------------------------------------------------------

#define TPB 256
#define GPB 8  // 32-lane groups per 256-thread block

__device__ __forceinline__ uint32_t f2bf(float f) {
    uint32_t u = __float_as_uint(f);
    return (u + 0x7FFFu + ((u >> 16) & 1u)) >> 16;  // RNE
}
__device__ __forceinline__ uint32_t pack2(float re, float im) {
    return f2bf(re) | (f2bf(im) << 16);
}
__device__ __forceinline__ float bflo(uint32_t p) { return __uint_as_float(p << 16); }
__device__ __forceinline__ float bfhi(uint32_t p) { return __uint_as_float(p & 0xFFFF0000u); }

// hist over edges: rowcnt (capturing per-edge slot), colcnt.
__global__ void k_hist(const int* __restrict__ row, const int* __restrict__ col,
                       int E, int* __restrict__ rowcnt, int* __restrict__ colcnt,
                       int* __restrict__ eoff) {
    int stride = gridDim.x * blockDim.x;
    for (int e = blockIdx.x * blockDim.x + threadIdx.x; e < E; e += stride) {
        eoff[e] = atomicAdd(&rowcnt[row[e]], 1);
        atomicAdd(&colcnt[col[e]], 1);
    }
}

__global__ void k_dis(const int* __restrict__ colcnt, float* __restrict__ dis, int N) {
    int i = blockIdx.x * blockDim.x + threadIdx.x;
    if (i < N) dis[i] = rsqrtf((float)colcnt[i] + 1.0f);  // +1 self loop
}

// xd[i] = pack2(x * dis) premultiplied gather operand
__global__ void k_pack(const float* __restrict__ xr, const float* __restrict__ xi,
                       const float* __restrict__ dis, uint32_t* __restrict__ xd,
                       long long ND) {
    long long i = (long long)blockIdx.x * blockDim.x + threadIdx.x;
    if (i < ND) {
        float dg = dis[i >> 5];
        xd[i] = pack2(xr[i] * dg, xi[i] * dg);
    }
}

// exclusive scan, 1024 elems per 256-thread block
__global__ void k_scan1(const int* __restrict__ in, int* __restrict__ out,
                        int* __restrict__ partials, int N) {
    __shared__ int sh[256];
    int t = threadIdx.x;
    int base = blockIdx.x * 1024 + t * 4;
    int v0 = (base + 0 < N) ? in[base + 0] : 0;
    int v1 = (base + 1 < N) ? in[base + 1] : 0;
    int v2 = (base + 2 < N) ? in[base + 2] : 0;
    int v3 = (base + 3 < N) ? in[base + 3] : 0;
    int s = v0 + v1 + v2 + v3;
    sh[t] = s;
    __syncthreads();
    for (int off = 1; off < 256; off <<= 1) {
        int add = (t >= off) ? sh[t - off] : 0;
        __syncthreads();
        sh[t] += add;
        __syncthreads();
    }
    int excl = sh[t] - s;
    if (base + 0 < N) out[base + 0] = excl;
    excl += v0;
    if (base + 1 < N) out[base + 1] = excl;
    excl += v1;
    if (base + 2 < N) out[base + 2] = excl;
    excl += v2;
    if (base + 3 < N) out[base + 3] = excl;
    if (t == 255) partials[blockIdx.x] = sh[255];
}

__global__ void k_scan2(int* __restrict__ partials, int nb) {
    if (threadIdx.x == 0 && blockIdx.x == 0) {
        int acc = 0;
        for (int i = 0; i < nb; ++i) { int v = partials[i]; partials[i] = acc; acc += v; }
    }
}

__global__ void k_scan3(int* __restrict__ out, const int* __restrict__ partials,
                        int N, int E) {
    int i = blockIdx.x * blockDim.x + threadIdx.x;
    if (i < N) out[i] += partials[i >> 10];
    if (i == 0) out[N] = E;
}

// entries[rowptr[r] + eoff[e]] = col[e]; no atomics.
__global__ void k_scatter(const int* __restrict__ row, const int* __restrict__ col,
                          const int* __restrict__ eoff, int E,
                          const int* __restrict__ rowptr, int* __restrict__ ecol) {
    int stride = gridDim.x * blockDim.x;
    for (int e = blockIdx.x * blockDim.x + threadIdx.x; e < E; e += stride)
        ecol[rowptr[row[e]] + eoff[e]] = col[e];
}

// Gather-accumulate of premultiplied packed rows over one node's edge list.
// Lane d owns dim d. Entry cols loaded coalesced (lane j -> edge base+j),
// addresses distributed via shfl (pure VALU), 16 gathers in flight.
__device__ __forceinline__ void edge_accum(const int* __restrict__ ecol,
                                           const uint32_t* __restrict__ hb,
                                           int beg, int end, int d,
                                           float& aR, float& aI) {
    for (int base = beg; base < end; base += 32) {
        int lim = end - base;
        if (lim > 32) lim = 32;
        int cv = (d < lim) ? ecol[base + d] : 0;
        int j = 0;
        for (; j + 16 <= lim; j += 16) {
            uint32_t p[16];
            #pragma unroll
            for (int k = 0; k < 16; ++k) {
                int c = __shfl(cv, j + k, 32);
                p[k] = hb[(size_t)c * 32 + d];
            }
            #pragma unroll
            for (int k = 0; k < 16; ++k) { aR += bflo(p[k]); aI += bfhi(p[k]); }
        }
        for (; j + 4 <= lim; j += 4) {
            uint32_t p[4];
            #pragma unroll
            for (int k = 0; k < 4; ++k) {
                int c = __shfl(cv, j + k, 32);
                p[k] = hb[(size_t)c * 32 + d];
            }
            #pragma unroll
            for (int k = 0; k < 4; ++k) { aR += bflo(p[k]); aI += bfhi(p[k]); }
        }
        for (; j < lim; ++j) {
            int c = __shfl(cv, j, 32);
            uint32_t p = hb[(size_t)c * 32 + d];
            aR += bflo(p);
            aI += bfhi(p);
        }
    }
}

// First propagate: fo = dis * (sum xd[c] + x*dis); writes fo2 (f32) + fod (packed).
__global__ void k_prop1(const int* __restrict__ rowptr, const int* __restrict__ ecol,
                        const float* __restrict__ dis,
                        const float* __restrict__ xr, const float* __restrict__ xi,
                        const uint32_t* __restrict__ xd,
                        float2* __restrict__ fo2, uint32_t* __restrict__ fod, int N) {
    int g = blockIdx.x * GPB + (threadIdx.x >> 5);
    int d = threadIdx.x & 31;
    if (g >= N) return;
    int beg = rowptr[g], end = rowptr[g + 1];
    float dg = dis[g];
    long long gd = (long long)g * 32 + d;
    float sR = 0.f, sI = 0.f;
    edge_accum(ecol, xd, beg, end, d, sR, sI);
    float foR = dg * (sR + xr[gd] * dg);
    float foI = dg * (sI + xi[gd] * dg);
    fo2[gd] = make_float2(foR, foI);
    fod[gd] = pack2(foR * dg, foI * dg);  // premultiplied for 2nd propagate
}

// Second propagate fused with final combine + |psi|^2 reduction.
__global__ void k_prop_final(const int* __restrict__ rowptr, const int* __restrict__ ecol,
                             const float* __restrict__ dis,
                             const float* __restrict__ xr, const float* __restrict__ xi,
                             const float2* __restrict__ fo2,
                             const uint32_t* __restrict__ fod,
                             const float* __restrict__ tptr, const float* __restrict__ dptr,
                             float* __restrict__ out, int N, int interleaved,
                             float* __restrict__ S) {
    int g = blockIdx.x * GPB + (threadIdx.x >> 5);
    int d = threadIdx.x & 31;
    bool valid = g < N;
    float er = 0.f, ei = 0.f;
    if (valid) {
        int beg = rowptr[g], end = rowptr[g + 1];
        float dg = dis[g];
        long long gd = (long long)g * 32 + d;
        float sR = 0.f, sI = 0.f;
        edge_accum(ecol, fod, beg, end, d, sR, sI);
        float2 fo = fo2[gd];
        float soR = dg * (sR + fo.x * dg);
        float soI = dg * (sI + fo.y * dg);
        float c1  = tptr[0] * dptr[0];
        float c2h = 0.5f * c1 * c1;
        er = xr[gd] - c1 * fo.y - c2h * soR;
        ei = xi[gd] + c1 * fo.x - c2h * soI;
        if (interleaved) {
            out[N + 2 * gd]     = er;
            out[N + 2 * gd + 1] = ei;
        } else {
            out[N + gd] = er;
        }
    }
    float wv = er * er + ei * ei;
    #pragma unroll
    for (int off = 16; off; off >>= 1) wv += __shfl_xor(wv, off, 32);
    if (valid && ((threadIdx.x & 31) == 0)) out[g] = wv;  // unnormalized w
    __shared__ float ls[GPB];
    int grp = threadIdx.x >> 5;
    if ((threadIdx.x & 31) == 0) ls[grp] = valid ? wv : 0.f;
    __syncthreads();
    if (threadIdx.x == 0) {
        float bs = 0.f;
        #pragma unroll
        for (int i = 0; i < GPB; ++i) bs += ls[i];
        atomicAdd(S, bs);
    }
}

__global__ void k_norm(float* __restrict__ w, int N, const float* __restrict__ S) {
    int i = blockIdx.x * blockDim.x + threadIdx.x;
    if (i >= N) return;
    float s = *S;
    w[i] = (s > 1e-8f) ? w[i] * ((float)N / s) : 1.0f;
}

extern "C" void kernel_launch(void* const* d_in, const int* in_sizes, int n_in,
                              void* d_out, int out_size, void* d_ws, size_t ws_size,
                              hipStream_t stream) {
    const float* xr   = (const float*)d_in[0];
    const float* xi   = (const float*)d_in[1];
    const int*   eidx = (const int*)d_in[2];
    const float* tptr = (const float*)d_in[3];
    const float* dptr = (const float*)d_in[4];

    const int N = in_sizes[0] / 32;
    const int E = in_sizes[2] / 2;
    const int* row = eidx;
    const int* col = eidx + E;
    const long long ND = (long long)N * 32;
    const int NB = (N + 1023) / 1024;

    // ws layout (4B units):
    // [rowcnt N | colcnt N | S 1]  <- zeroed
    // [eoff E | rowptr N+1 | partials nbpad | dis N | xd ND | fo2 2*ND | fod ND | ecol E]
    int*      rowcnt   = (int*)d_ws;
    int*      colcnt   = rowcnt + N;
    float*    S        = (float*)(colcnt + N);
    int*      eoff     = (int*)(S + 1);
    int*      rowptr   = eoff + E;
    int       nbpad    = (NB + 4) & ~1;
    int*      partials = rowptr + (N + 1);
    float*    dis      = (float*)(partials + nbpad);
    uint32_t* xd       = (uint32_t*)(dis + N);
    size_t    off      = (size_t)((char*)(xd + ND) - (char*)d_ws);
    off = (off + 15) & ~(size_t)15;  // 16B align for float2
    float2*   fo2      = (float2*)((char*)d_ws + off);
    uint32_t* fod      = (uint32_t*)(fo2 + ND);
    int*      ecol     = (int*)(fod + ND);

    hipMemsetAsync(d_ws, 0, (size_t)(2 * N + 1) * sizeof(int), stream);

    int interleaved = (out_size >= (int)(N + 2 * ND)) ? 1 : 0;
    float* out = (float*)d_out;

    k_hist<<<2048, TPB, 0, stream>>>(row, col, E, rowcnt, colcnt, eoff);
    k_dis<<<(N + TPB - 1) / TPB, TPB, 0, stream>>>(colcnt, dis, N);
    k_pack<<<(int)((ND + TPB - 1) / TPB), TPB, 0, stream>>>(xr, xi, dis, xd, ND);
    k_scan1<<<NB, TPB, 0, stream>>>(rowcnt, rowptr, partials, N);
    k_scan2<<<1, 64, 0, stream>>>(partials, NB);
    k_scan3<<<(N + TPB - 1) / TPB, TPB, 0, stream>>>(rowptr, partials, N, E);
    k_scatter<<<2048, TPB, 0, stream>>>(row, col, eoff, E, rowptr, ecol);

    int pblocks = (N + GPB - 1) / GPB;
    k_prop1<<<pblocks, TPB, 0, stream>>>(rowptr, ecol, dis, xr, xi, xd, fo2, fod, N);
    k_prop_final<<<pblocks, TPB, 0, stream>>>(rowptr, ecol, dis, xr, xi, fo2, fod,
                                              tptr, dptr, out, N, interleaved, S);
    k_norm<<<(N + TPB - 1) / TPB, TPB, 0, stream>>>(out, N, S);
}